// Round 1
// baseline (476.889 us; speedup 1.0000x reference)
//
#include <hip/hip_runtime.h>
#include <hip/hip_bf16.h>

// Problem constants (fixed by the reference)
#define N_CURVES 2097152   // B*G*C
#define NG       16384     // B*G groups
#define B_PIC    256
#define G_PER_B  64
#define NSLOT    64        // contention-spreading slots for BN12 stats

__device__ __forceinline__ float leaky(float v) {
    // leaky_relu slope 0.01: max(v, 0.01v) is exact for both signs
    return fmaxf(v, 0.01f * v);
}

// ---------------------------------------------------------------------------
// Kernel A: per-curve MLP 32->24->12 (leaky), emit per-group sums of h (pre-BN)
// and 64-slot-spread global sums / sums-of-squares per channel for BN stats.
// BN commutes with the segment mean (affine), so h is never materialized.
// ---------------------------------------------------------------------------
__global__ __launch_bounds__(256) void kA(const float* __restrict__ x,
                                          const float* __restrict__ w1,
                                          const float* __restrict__ b1,
                                          const float* __restrict__ w2,
                                          const float* __restrict__ b2,
                                          float* __restrict__ partials,   // [NSLOT][24]
                                          float* __restrict__ groupSums)  // [NG][12]
{
    const int tid = threadIdx.x;
    const size_t curve = (size_t)blockIdx.x * 256 + tid;

    // load this curve's 32 features (8 x float4; each 128B line used fully by one thread)
    float xr[32];
    const float4* xv = (const float4*)(x + curve * 32);
#pragma unroll
    for (int i = 0; i < 8; ++i) {
        float4 v = xv[i];
        xr[4 * i + 0] = v.x; xr[4 * i + 1] = v.y;
        xr[4 * i + 2] = v.z; xr[4 * i + 3] = v.w;
    }

    // layer 1: 32 -> 24  (weights via wave-uniform indices -> s_load path)
    float h1[24];
#pragma unroll
    for (int j = 0; j < 24; ++j) {
        float acc = b1[j];
#pragma unroll
        for (int k = 0; k < 32; ++k) acc = fmaf(xr[k], w1[j * 32 + k], acc);
        h1[j] = leaky(acc);
    }

    // layer 2: 24 -> 12
    float h2[12];
#pragma unroll
    for (int j = 0; j < 12; ++j) {
        float acc = b2[j];
#pragma unroll
        for (int k = 0; k < 24; ++k) acc = fmaf(h1[k], w2[j * 24 + k], acc);
        h2[j] = leaky(acc);
    }

    // intra-group reduction: group = 128 consecutive curves = 2 waves.
    __shared__ float wsum[4][12];
    __shared__ float wsq[4][12];
    const int lane = tid & 63, wid = tid >> 6;
#pragma unroll
    for (int c = 0; c < 12; ++c) {
        float v = h2[c];
        float q = v * v;
#pragma unroll
        for (int off = 32; off >= 1; off >>= 1) {
            v += __shfl_down(v, off);
            q += __shfl_down(q, off);
        }
        if (lane == 0) { wsum[wid][c] = v; wsq[wid][c] = q; }
    }
    __syncthreads();

    if (tid < 12) {
        const int c = tid;
        const float g0 = wsum[0][c] + wsum[1][c];   // group 2*bid
        const float g1 = wsum[2][c] + wsum[3][c];   // group 2*bid+1
        groupSums[(size_t)(2 * blockIdx.x) * 12 + c]     = g0;
        groupSums[(size_t)(2 * blockIdx.x + 1) * 12 + c] = g1;
        const int slot = blockIdx.x & (NSLOT - 1);  // spread same-address contention 64x
        atomicAdd(&partials[slot * 24 + c], g0 + g1);
        const float q = wsq[0][c] + wsq[1][c] + wsq[2][c] + wsq[3][c];
        atomicAdd(&partials[slot * 24 + 12 + c], q);
    }
}

// ---------------------------------------------------------------------------
// Kernel B: one wave per picture. Finalize BN12, cor = leaky(dist@wd.T+bd),
// three pooling levels, write sum_pic[b][36] = [L1 | L2 | L3].
// ---------------------------------------------------------------------------
__global__ __launch_bounds__(64) void kB(const float* __restrict__ partials,
                                         const float* __restrict__ groupSums,
                                         const float* __restrict__ dist,     // [B][G][2][5]
                                         const float* __restrict__ wd,       // [12][5]
                                         const float* __restrict__ bd,
                                         const float* __restrict__ gamma12,
                                         const float* __restrict__ beta12,
                                         float* __restrict__ sum_pic)        // [B][36]
{
    __shared__ float scale[12], shift[12];
    const int g = threadIdx.x;      // group within picture
    const int b = blockIdx.x;       // picture

    if (g < 12) {
        float S = 0.f, Q = 0.f;
        for (int s = 0; s < NSLOT; ++s) {
            S += partials[s * 24 + g];
            Q += partials[s * 24 + 12 + g];
        }
        const float mu  = S * (1.0f / (float)N_CURVES);
        const float var = Q * (1.0f / (float)N_CURVES) - mu * mu;  // biased, matches ref
        const float inv = rsqrtf(var + 1e-5f);
        scale[g] = inv * gamma12[g];
        shift[g] = beta12[g] - mu * inv * gamma12[g];
    }
    __syncthreads();

    const float* dm = dist + (size_t)(b * G_PER_B + g) * 2 * 5;  // [.,.,0,:]
    const float d0 = dm[0], d1 = dm[1], d2 = dm[2], d3 = dm[3], d4 = dm[4];
    const float* gs = groupSums + (size_t)(b * G_PER_B + g) * 12;

    float a1[12], a2[12], a3[12];
#pragma unroll
    for (int d = 0; d < 12; ++d) {
        float cor = bd[d];
        cor = fmaf(d0, wd[d * 5 + 0], cor);
        cor = fmaf(d1, wd[d * 5 + 1], cor);
        cor = fmaf(d2, wd[d * 5 + 2], cor);
        cor = fmaf(d3, wd[d * 5 + 3], cor);
        cor = fmaf(d4, wd[d * 5 + 4], cor);
        cor = leaky(cor);
        float t = gs[d] * (1.0f / 128.0f);       // group mean (pre-BN)
        t = t * scale[d] + shift[d];             // BN12 applied post-mean (affine commute)
        a1[d] = t;
        a2[d] = cor * t;
        a3[d] = cor * cor * t;
    }

    // reduce the 36 accumulators over the 64 groups (single wave)
#pragma unroll
    for (int d = 0; d < 12; ++d) {
        float v1 = a1[d], v2 = a2[d], v3 = a3[d];
#pragma unroll
        for (int off = 32; off >= 1; off >>= 1) {
            v1 += __shfl_down(v1, off);
            v2 += __shfl_down(v2, off);
            v3 += __shfl_down(v3, off);
        }
        if (g == 0) {
            sum_pic[b * 36 + d]      = v1 * (1.0f / 64.0f);
            sum_pic[b * 36 + 12 + d] = v2 * (1.0f / 64.0f);
            sum_pic[b * 36 + 24 + d] = v3 * (1.0f / 64.0f);
        }
    }
}

// ---------------------------------------------------------------------------
// Kernel C: single block. BN36 over the 256 pictures, then 36->18->8->2 MLP
// + softmax. Thread t owns picture t. Output: p2 (256x8) then p3 (256x2).
// ---------------------------------------------------------------------------
__global__ __launch_bounds__(256) void kC(const float* __restrict__ sum_pic,
                                          const float* __restrict__ gamma36,
                                          const float* __restrict__ beta36,
                                          const float* __restrict__ wp1,
                                          const float* __restrict__ bp1,
                                          const float* __restrict__ wp2,
                                          const float* __restrict__ bp2,
                                          const float* __restrict__ wp3,
                                          const float* __restrict__ bp3,
                                          float* __restrict__ out)
{
    const int t = threadIdx.x;  // picture
    float s[36];
#pragma unroll
    for (int c = 0; c < 36; ++c) s[c] = sum_pic[t * 36 + c];

    __shared__ float mu[36], inv[36];
    __shared__ float wred[4], wred2[4];
    const int lane = t & 63, wid = t >> 6;

    for (int c = 0; c < 36; ++c) {
        float v = s[c];
        float q = v * v;
#pragma unroll
        for (int off = 32; off >= 1; off >>= 1) {
            v += __shfl_down(v, off);
            q += __shfl_down(q, off);
        }
        if (lane == 0) { wred[wid] = v; wred2[wid] = q; }
        __syncthreads();
        if (t == 0) {
            const float S = wred[0] + wred[1] + wred[2] + wred[3];
            const float Q = wred2[0] + wred2[1] + wred2[2] + wred2[3];
            const float m = S * (1.0f / 256.0f);
            mu[c]  = m;
            inv[c] = rsqrtf(Q * (1.0f / 256.0f) - m * m + 1e-5f);
        }
        __syncthreads();
    }

#pragma unroll
    for (int c = 0; c < 36; ++c)
        s[c] = (s[c] - mu[c]) * inv[c] * gamma36[c] + beta36[c];

    float p1[18];
#pragma unroll
    for (int j = 0; j < 18; ++j) {
        float acc = bp1[j];
#pragma unroll
        for (int k = 0; k < 36; ++k) acc = fmaf(s[k], wp1[j * 36 + k], acc);
        p1[j] = leaky(acc);
    }
    float p2[8];
#pragma unroll
    for (int j = 0; j < 8; ++j) {
        float acc = bp2[j];
#pragma unroll
        for (int k = 0; k < 18; ++k) acc = fmaf(p1[k], wp2[j * 18 + k], acc);
        p2[j] = leaky(acc);
    }
    float l0 = bp3[0], l1 = bp3[1];
#pragma unroll
    for (int k = 0; k < 8; ++k) {
        l0 = fmaf(p2[k], wp3[k], l0);
        l1 = fmaf(p2[k], wp3[8 + k], l1);
    }
    const float m  = fmaxf(l0, l1);
    const float e0 = __expf(l0 - m);
    const float e1 = __expf(l1 - m);
    const float rd = 1.0f / (e0 + e1);

#pragma unroll
    for (int j = 0; j < 8; ++j) out[t * 8 + j] = p2[j];   // p2 block: [0, 2048)
    out[2048 + t * 2 + 0] = e0 * rd;                       // p3 block: [2048, 2560)
    out[2048 + t * 2 + 1] = e1 * rd;
}

extern "C" void kernel_launch(void* const* d_in, const int* in_sizes, int n_in,
                              void* d_out, int out_size, void* d_ws, size_t ws_size,
                              hipStream_t stream) {
    const float* x       = (const float*)d_in[0];
    const float* dist    = (const float*)d_in[1];
    // d_in[2] segment_ids: arange(N)//C -> uniform contiguous segments; implicit in indexing
    const float* w1      = (const float*)d_in[3];
    const float* b1      = (const float*)d_in[4];
    const float* w2      = (const float*)d_in[5];
    const float* b2      = (const float*)d_in[6];
    const float* gamma12 = (const float*)d_in[7];
    const float* beta12  = (const float*)d_in[8];
    const float* wd      = (const float*)d_in[9];
    const float* bd      = (const float*)d_in[10];
    const float* gamma36 = (const float*)d_in[11];
    const float* beta36  = (const float*)d_in[12];
    const float* wp1     = (const float*)d_in[13];
    const float* bp1     = (const float*)d_in[14];
    const float* wp2     = (const float*)d_in[15];
    const float* bp2     = (const float*)d_in[16];
    const float* wp3     = (const float*)d_in[17];
    const float* bp3     = (const float*)d_in[18];

    float* ws        = (float*)d_ws;
    float* partials  = ws;                          // NSLOT*24 floats
    float* groupSums = ws + NSLOT * 24;             // NG*12 floats
    float* sum_pic   = groupSums + (size_t)NG * 12; // B_PIC*36 floats

    // ws is re-poisoned to 0xAA before every launch; zero only the atomic targets
    hipMemsetAsync(partials, 0, NSLOT * 24 * sizeof(float), stream);

    kA<<<N_CURVES / 256, 256, 0, stream>>>(x, w1, b1, w2, b2, partials, groupSums);
    kB<<<B_PIC, G_PER_B, 0, stream>>>(partials, groupSums, dist, wd, bd,
                                      gamma12, beta12, sum_pic);
    kC<<<1, 256, 0, stream>>>(sum_pic, gamma36, beta36,
                              wp1, bp1, wp2, bp2, wp3, bp3, (float*)d_out);
}

// Round 2
// 445.026 us; speedup vs baseline: 1.0716x; 1.0716x over previous
//
#include <hip/hip_runtime.h>
#include <hip/hip_bf16.h>

// Problem constants (fixed by the reference)
#define N_CURVES 2097152   // B*G*C
#define NG       16384     // B*G groups
#define B_PIC    256
#define G_PER_B  64
#define NSLOT    64        // contention-spreading slots for BN12 stats

__device__ __forceinline__ float leaky(float v) {
    // leaky_relu slope 0.01: max(v, 0.01v) is exact for both signs
    return fmaxf(v, 0.01f * v);
}

// ---------------------------------------------------------------------------
// Kernel A: per-curve MLP 32->24->12 (leaky), emit per-group sums of h (pre-BN)
// and 64-slot-spread global sums / sums-of-squares per channel for BN stats.
// BN commutes with the segment mean (affine), so h is never materialized.
//
// R1 change: x is staged through LDS. Global loads are fully coalesced
// (lane-consecutive float4), LDS uses a 16B-granule XOR swizzle so both the
// write phase and the per-curve read phase are uniform 8-deep (= ds_*_b128
// baseline cost, no conflict penalty). This removes the 64-lines-per-
// instruction strided pattern that was hammering the TA pipe in R0.
// ---------------------------------------------------------------------------
__global__ __launch_bounds__(256, 4) void kA(const float* __restrict__ x,
                                             const float* __restrict__ w1,
                                             const float* __restrict__ b1,
                                             const float* __restrict__ w2,
                                             const float* __restrict__ b2,
                                             float* __restrict__ partials,   // [NSLOT][24]
                                             float* __restrict__ groupSums)  // [NG][12]
{
    // 256 curves per block = 2 groups of 128. 32 KB x-stage + small reduce bufs.
    __shared__ float4 xs[256 * 8];      // curve c, 16B-chunk j at xs[c*8 + (j ^ (c&7))]
    __shared__ float wsum[4][12];
    __shared__ float wsq[4][12];

    const int tid = threadIdx.x;
    const size_t blockBase = (size_t)blockIdx.x * 2048;   // float4 index of block's x

    // ---- coalesced global -> swizzled LDS ----
    const float4* __restrict__ xg = (const float4*)x;
#pragma unroll
    for (int i = 0; i < 8; ++i) {
        const int idx = i * 256 + tid;          // float4 index within block's region
        const float4 v = xg[blockBase + idx];   // lane-consecutive: fully coalesced
        const int c = idx >> 3;                 // curve within block
        const int j = idx & 7;                  // 16B chunk within curve
        xs[c * 8 + (j ^ (c & 7))] = v;
    }
    __syncthreads();

    // ---- per-curve read (swizzled, uniform 8-deep banking) ----
    float xr[32];
#pragma unroll
    for (int j = 0; j < 8; ++j) {
        const float4 v = xs[tid * 8 + (j ^ (tid & 7))];
        xr[4 * j + 0] = v.x; xr[4 * j + 1] = v.y;
        xr[4 * j + 2] = v.z; xr[4 * j + 3] = v.w;
    }

    // ---- layer 1: 32 -> 24 (weights wave-uniform -> s_load path) ----
    float h1[24];
#pragma unroll
    for (int j = 0; j < 24; ++j) {
        float acc = b1[j];
#pragma unroll
        for (int k = 0; k < 32; ++k) acc = fmaf(xr[k], w1[j * 32 + k], acc);
        h1[j] = leaky(acc);
    }

    // ---- layer 2: 24 -> 12 ----
    float h2[12];
#pragma unroll
    for (int j = 0; j < 12; ++j) {
        float acc = b2[j];
#pragma unroll
        for (int k = 0; k < 24; ++k) acc = fmaf(h1[k], w2[j * 24 + k], acc);
        h2[j] = leaky(acc);
    }

    // ---- intra-group reduction: group = 128 consecutive curves = 2 waves ----
    const int lane = tid & 63, wid = tid >> 6;
#pragma unroll
    for (int c = 0; c < 12; ++c) {
        float v = h2[c];
        float q = v * v;
#pragma unroll
        for (int off = 32; off >= 1; off >>= 1) {
            v += __shfl_down(v, off);
            q += __shfl_down(q, off);
        }
        if (lane == 0) { wsum[wid][c] = v; wsq[wid][c] = q; }
    }
    __syncthreads();

    if (tid < 12) {
        const int c = tid;
        const float g0 = wsum[0][c] + wsum[1][c];   // group 2*bid
        const float g1 = wsum[2][c] + wsum[3][c];   // group 2*bid+1
        groupSums[(size_t)(2 * blockIdx.x) * 12 + c]     = g0;
        groupSums[(size_t)(2 * blockIdx.x + 1) * 12 + c] = g1;
        const int slot = blockIdx.x & (NSLOT - 1);  // spread same-address contention 64x
        atomicAdd(&partials[slot * 24 + c], g0 + g1);
        const float q = wsq[0][c] + wsq[1][c] + wsq[2][c] + wsq[3][c];
        atomicAdd(&partials[slot * 24 + 12 + c], q);
    }
}

// ---------------------------------------------------------------------------
// Kernel B: one wave per picture. Finalize BN12, cor = leaky(dist@wd.T+bd),
// three pooling levels, write sum_pic[b][36] = [L1 | L2 | L3].
// ---------------------------------------------------------------------------
__global__ __launch_bounds__(64) void kB(const float* __restrict__ partials,
                                         const float* __restrict__ groupSums,
                                         const float* __restrict__ dist,     // [B][G][2][5]
                                         const float* __restrict__ wd,       // [12][5]
                                         const float* __restrict__ bd,
                                         const float* __restrict__ gamma12,
                                         const float* __restrict__ beta12,
                                         float* __restrict__ sum_pic)        // [B][36]
{
    __shared__ float scale[12], shift[12];
    const int g = threadIdx.x;      // group within picture
    const int b = blockIdx.x;       // picture

    if (g < 12) {
        float S = 0.f, Q = 0.f;
        for (int s = 0; s < NSLOT; ++s) {
            S += partials[s * 24 + g];
            Q += partials[s * 24 + 12 + g];
        }
        const float mu  = S * (1.0f / (float)N_CURVES);
        const float var = Q * (1.0f / (float)N_CURVES) - mu * mu;  // biased, matches ref
        const float inv = rsqrtf(var + 1e-5f);
        scale[g] = inv * gamma12[g];
        shift[g] = beta12[g] - mu * inv * gamma12[g];
    }
    __syncthreads();

    const float* dm = dist + (size_t)(b * G_PER_B + g) * 2 * 5;  // [.,.,0,:]
    const float d0 = dm[0], d1 = dm[1], d2 = dm[2], d3 = dm[3], d4 = dm[4];
    const float* gs = groupSums + (size_t)(b * G_PER_B + g) * 12;

    float a1[12], a2[12], a3[12];
#pragma unroll
    for (int d = 0; d < 12; ++d) {
        float cor = bd[d];
        cor = fmaf(d0, wd[d * 5 + 0], cor);
        cor = fmaf(d1, wd[d * 5 + 1], cor);
        cor = fmaf(d2, wd[d * 5 + 2], cor);
        cor = fmaf(d3, wd[d * 5 + 3], cor);
        cor = fmaf(d4, wd[d * 5 + 4], cor);
        cor = leaky(cor);
        float t = gs[d] * (1.0f / 128.0f);       // group mean (pre-BN)
        t = t * scale[d] + shift[d];             // BN12 applied post-mean (affine commute)
        a1[d] = t;
        a2[d] = cor * t;
        a3[d] = cor * cor * t;
    }

    // reduce the 36 accumulators over the 64 groups (single wave)
#pragma unroll
    for (int d = 0; d < 12; ++d) {
        float v1 = a1[d], v2 = a2[d], v3 = a3[d];
#pragma unroll
        for (int off = 32; off >= 1; off >>= 1) {
            v1 += __shfl_down(v1, off);
            v2 += __shfl_down(v2, off);
            v3 += __shfl_down(v3, off);
        }
        if (g == 0) {
            sum_pic[b * 36 + d]      = v1 * (1.0f / 64.0f);
            sum_pic[b * 36 + 12 + d] = v2 * (1.0f / 64.0f);
            sum_pic[b * 36 + 24 + d] = v3 * (1.0f / 64.0f);
        }
    }
}

// ---------------------------------------------------------------------------
// Kernel C: single block. BN36 over the 256 pictures, then 36->18->8->2 MLP
// + softmax. Thread t owns picture t. Output: p2 (256x8) then p3 (256x2).
// R1 change: BN36 stats computed in parallel via padded-LDS transpose
// (2 barriers total, was 72).
// ---------------------------------------------------------------------------
__global__ __launch_bounds__(256) void kC(const float* __restrict__ sum_pic,
                                          const float* __restrict__ gamma36,
                                          const float* __restrict__ beta36,
                                          const float* __restrict__ wp1,
                                          const float* __restrict__ bp1,
                                          const float* __restrict__ wp2,
                                          const float* __restrict__ bp2,
                                          const float* __restrict__ wp3,
                                          const float* __restrict__ bp3,
                                          float* __restrict__ out)
{
    const int t = threadIdx.x;  // picture
    __shared__ float sm[256 * 37];      // padded: bank = (37t+c)%32, 5 coprime 32
    __shared__ float scale[36], shift[36];

    float s[36];
#pragma unroll
    for (int c = 0; c < 36; ++c) {
        s[c] = sum_pic[t * 36 + c];
        sm[t * 37 + c] = s[c];
    }
    __syncthreads();

    if (t < 36) {
        float S = 0.f, Q = 0.f;
        for (int i = 0; i < 256; ++i) {
            const float v = sm[i * 37 + t];
            S += v;
            Q += v * v;
        }
        const float m   = S * (1.0f / 256.0f);
        const float inv = rsqrtf(Q * (1.0f / 256.0f) - m * m + 1e-5f);
        scale[t] = inv * gamma36[t];
        shift[t] = beta36[t] - m * inv * gamma36[t];
    }
    __syncthreads();

#pragma unroll
    for (int c = 0; c < 36; ++c)
        s[c] = s[c] * scale[c] + shift[c];

    float p1[18];
#pragma unroll
    for (int j = 0; j < 18; ++j) {
        float acc = bp1[j];
#pragma unroll
        for (int k = 0; k < 36; ++k) acc = fmaf(s[k], wp1[j * 36 + k], acc);
        p1[j] = leaky(acc);
    }
    float p2[8];
#pragma unroll
    for (int j = 0; j < 8; ++j) {
        float acc = bp2[j];
#pragma unroll
        for (int k = 0; k < 18; ++k) acc = fmaf(p1[k], wp2[j * 18 + k], acc);
        p2[j] = leaky(acc);
    }
    float l0 = bp3[0], l1 = bp3[1];
#pragma unroll
    for (int k = 0; k < 8; ++k) {
        l0 = fmaf(p2[k], wp3[k], l0);
        l1 = fmaf(p2[k], wp3[8 + k], l1);
    }
    const float m  = fmaxf(l0, l1);
    const float e0 = __expf(l0 - m);
    const float e1 = __expf(l1 - m);
    const float rd = 1.0f / (e0 + e1);

#pragma unroll
    for (int j = 0; j < 8; ++j) out[t * 8 + j] = p2[j];   // p2 block: [0, 2048)
    out[2048 + t * 2 + 0] = e0 * rd;                       // p3 block: [2048, 2560)
    out[2048 + t * 2 + 1] = e1 * rd;
}

extern "C" void kernel_launch(void* const* d_in, const int* in_sizes, int n_in,
                              void* d_out, int out_size, void* d_ws, size_t ws_size,
                              hipStream_t stream) {
    const float* x       = (const float*)d_in[0];
    const float* dist    = (const float*)d_in[1];
    // d_in[2] segment_ids: arange(N)//C -> uniform contiguous segments; implicit in indexing
    const float* w1      = (const float*)d_in[3];
    const float* b1      = (const float*)d_in[4];
    const float* w2      = (const float*)d_in[5];
    const float* b2      = (const float*)d_in[6];
    const float* gamma12 = (const float*)d_in[7];
    const float* beta12  = (const float*)d_in[8];
    const float* wd      = (const float*)d_in[9];
    const float* bd      = (const float*)d_in[10];
    const float* gamma36 = (const float*)d_in[11];
    const float* beta36  = (const float*)d_in[12];
    const float* wp1     = (const float*)d_in[13];
    const float* bp1     = (const float*)d_in[14];
    const float* wp2     = (const float*)d_in[15];
    const float* bp2     = (const float*)d_in[16];
    const float* wp3     = (const float*)d_in[17];
    const float* bp3     = (const float*)d_in[18];

    float* ws        = (float*)d_ws;
    float* partials  = ws;                          // NSLOT*24 floats
    float* groupSums = ws + NSLOT * 24;             // NG*12 floats
    float* sum_pic   = groupSums + (size_t)NG * 12; // B_PIC*36 floats

    // ws is re-poisoned to 0xAA before every launch; zero only the atomic targets
    hipMemsetAsync(partials, 0, NSLOT * 24 * sizeof(float), stream);

    kA<<<N_CURVES / 256, 256, 0, stream>>>(x, w1, b1, w2, b2, partials, groupSums);
    kB<<<B_PIC, G_PER_B, 0, stream>>>(partials, groupSums, dist, wd, bd,
                                      gamma12, beta12, sum_pic);
    kC<<<1, 256, 0, stream>>>(sum_pic, gamma36, beta36,
                              wp1, bp1, wp2, bp2, wp3, bp3, (float*)d_out);
}

// Round 3
// 439.592 us; speedup vs baseline: 1.0848x; 1.0124x over previous
//
#include <hip/hip_runtime.h>
#include <hip/hip_bf16.h>

// Problem constants (fixed by the reference)
#define N_CURVES 2097152   // B*G*C
#define NG       16384     // B*G groups
#define B_PIC    256
#define G_PER_B  64
#define NSLOT    64        // contention-spreading slots for BN12 stats

__device__ __forceinline__ float leaky(float v) {
    // leaky_relu slope 0.01: max(v, 0.01v) is exact for both signs
    return fmaxf(v, 0.01f * v);
}

// ---------------------------------------------------------------------------
// Kernel A: per-curve MLP 32->24->12 (leaky), emit per-group sums of h (pre-BN)
// and 64-slot-spread global sums / sums-of-squares per channel for BN stats.
// BN commutes with the segment mean (affine), so h is never materialized.
//
// R2 changes vs R1:
//  - global->LDS staging via __builtin_amdgcn_global_load_lds width=16 (DMA,
//    no VGPR round-trip, no ds_write). The 16B-granule XOR swizzle moved to
//    the per-lane GLOBAL address (coalescing unaffected: same 1KB segment,
//    permuted within); LDS side is the required wave-linear lane*16 pattern.
//  - layer2 folded into layer1 (h2 accumulates as each h1[j] retires): live
//    regs ~65 -> __launch_bounds__(256,5); 5 blocks/CU x 32KB = 160KB LDS.
//  - shuffle-butterfly reduction (290 insts/thread) replaced by 12 LDS
//    stores/thread + one-wave 128-deep tail sum (squares computed in tail).
// ---------------------------------------------------------------------------
__global__ __launch_bounds__(256, 5) void kA(const float* __restrict__ x,
                                             const float* __restrict__ w1,
                                             const float* __restrict__ b1,
                                             const float* __restrict__ w2,
                                             const float* __restrict__ b2,
                                             float* __restrict__ partials,   // [NSLOT][24]
                                             float* __restrict__ groupSums)  // [NG][12]
{
    // 32 KB LDS, reused: phase 1 = x stage (2048 float4), phase 2 = h2 matrix
    __shared__ __align__(16) char smem[32768];
    float4* xs = (float4*)smem;          // [2048] swizzled x image
    float*  sm = (float*)smem;           // [256][14] h2 (padded, 14.3 KB)

    const int tid = threadIdx.x;
    const size_t blockBase = (size_t)blockIdx.x * 2048;   // float4 index of block's x
    const float4* __restrict__ xg = (const float4*)x;

    // ---- phase 1: global -> LDS DMA, swizzle applied on the global side ----
    // LDS slot s holds global chunk  c*8 + ((s&7) ^ (c&7)),  c = s>>3.
#pragma unroll
    for (int i = 0; i < 8; ++i) {
        const int s  = i * 256 + tid;            // this lane's LDS float4 slot
        const int c  = s >> 3;
        const int j  = (s & 7) ^ (c & 7);        // global chunk for this slot
        const float4* gp = xg + blockBase + c * 8 + j;
        // wave-uniform LDS base: slots [i*256 + waveBase, +64)
        float4* lp = xs + (i * 256 + (tid & 192));
#if defined(__has_builtin) && __has_builtin(__builtin_amdgcn_global_load_lds)
        __builtin_amdgcn_global_load_lds(
            (const __attribute__((address_space(1))) void*)gp,
            (__attribute__((address_space(3))) void*)lp, 16, 0, 0);
#else
        xs[s] = *gp;   // fallback: explicit staged store
#endif
    }
    __syncthreads();

    // ---- per-curve read (swizzled => uniform bank spread, conflict-free) ----
    float xr[32];
#pragma unroll
    for (int j = 0; j < 8; ++j) {
        const float4 v = xs[tid * 8 + (j ^ (tid & 7))];
        xr[4 * j + 0] = v.x; xr[4 * j + 1] = v.y;
        xr[4 * j + 2] = v.z; xr[4 * j + 3] = v.w;
    }
    __syncthreads();   // xs dead after this; smem reused as sm below

    // ---- fused MLP: layer1 row j retires straight into layer2 accumulators ----
    float h2[12];
#pragma unroll
    for (int c = 0; c < 12; ++c) h2[c] = b2[c];
#pragma unroll
    for (int j = 0; j < 24; ++j) {
        float t = b1[j];
#pragma unroll
        for (int k = 0; k < 32; ++k) t = fmaf(xr[k], w1[j * 32 + k], t);
        t = leaky(t);
#pragma unroll
        for (int c = 0; c < 12; ++c) h2[c] = fmaf(t, w2[c * 24 + j], h2[c]);
    }
#pragma unroll
    for (int c = 0; c < 12; ++c) {
        h2[c] = leaky(h2[c]);
        sm[tid * 14 + c] = h2[c];        // pad 14: float2-aligned, even bank spread
    }
    __syncthreads();

    // ---- one-wave tail: 24 jobs (group g in {0,1} x channel c in [0,12)) ----
    if (tid < 24) {
        const int c = tid % 12;
        const int g = tid / 12;
        const float* base = sm + (size_t)g * 128 * 14 + c;
        float S0 = 0.f, S1 = 0.f, S2 = 0.f, S3 = 0.f;
        float Q0 = 0.f, Q1 = 0.f, Q2 = 0.f, Q3 = 0.f;
#pragma unroll 8
        for (int i = 0; i < 128; i += 4) {
            const float v0 = base[(i + 0) * 14];
            const float v1 = base[(i + 1) * 14];
            const float v2 = base[(i + 2) * 14];
            const float v3 = base[(i + 3) * 14];
            S0 += v0; Q0 = fmaf(v0, v0, Q0);
            S1 += v1; Q1 = fmaf(v1, v1, Q1);
            S2 += v2; Q2 = fmaf(v2, v2, Q2);
            S3 += v3; Q3 = fmaf(v3, v3, Q3);
        }
        const float S = (S0 + S1) + (S2 + S3);
        const float Q = (Q0 + Q1) + (Q2 + Q3);
        groupSums[(size_t)(2 * blockIdx.x + g) * 12 + c] = S;
        const int slot = blockIdx.x & (NSLOT - 1);  // spread contention 64x
        atomicAdd(&partials[slot * 24 + c], S);          // 2-way (g0+g1) per addr
        atomicAdd(&partials[slot * 24 + 12 + c], Q);
    }
}

// ---------------------------------------------------------------------------
// Kernel B: one wave per picture. Finalize BN12, cor = leaky(dist@wd.T+bd),
// three pooling levels, write sum_pic[b][36] = [L1 | L2 | L3].
// ---------------------------------------------------------------------------
__global__ __launch_bounds__(64) void kB(const float* __restrict__ partials,
                                         const float* __restrict__ groupSums,
                                         const float* __restrict__ dist,     // [B][G][2][5]
                                         const float* __restrict__ wd,       // [12][5]
                                         const float* __restrict__ bd,
                                         const float* __restrict__ gamma12,
                                         const float* __restrict__ beta12,
                                         float* __restrict__ sum_pic)        // [B][36]
{
    __shared__ float scale[12], shift[12];
    const int g = threadIdx.x;      // group within picture
    const int b = blockIdx.x;       // picture

    if (g < 12) {
        float S = 0.f, Q = 0.f;
        for (int s = 0; s < NSLOT; ++s) {
            S += partials[s * 24 + g];
            Q += partials[s * 24 + 12 + g];
        }
        const float mu  = S * (1.0f / (float)N_CURVES);
        const float var = Q * (1.0f / (float)N_CURVES) - mu * mu;  // biased, matches ref
        const float inv = rsqrtf(var + 1e-5f);
        scale[g] = inv * gamma12[g];
        shift[g] = beta12[g] - mu * inv * gamma12[g];
    }
    __syncthreads();

    const float* dm = dist + (size_t)(b * G_PER_B + g) * 2 * 5;  // [.,.,0,:]
    const float d0 = dm[0], d1 = dm[1], d2 = dm[2], d3 = dm[3], d4 = dm[4];
    const float* gs = groupSums + (size_t)(b * G_PER_B + g) * 12;

    float a1[12], a2[12], a3[12];
#pragma unroll
    for (int d = 0; d < 12; ++d) {
        float cor = bd[d];
        cor = fmaf(d0, wd[d * 5 + 0], cor);
        cor = fmaf(d1, wd[d * 5 + 1], cor);
        cor = fmaf(d2, wd[d * 5 + 2], cor);
        cor = fmaf(d3, wd[d * 5 + 3], cor);
        cor = fmaf(d4, wd[d * 5 + 4], cor);
        cor = leaky(cor);
        float t = gs[d] * (1.0f / 128.0f);       // group mean (pre-BN)
        t = t * scale[d] + shift[d];             // BN12 applied post-mean (affine commute)
        a1[d] = t;
        a2[d] = cor * t;
        a3[d] = cor * cor * t;
    }

    // reduce the 36 accumulators over the 64 groups (single wave)
#pragma unroll
    for (int d = 0; d < 12; ++d) {
        float v1 = a1[d], v2 = a2[d], v3 = a3[d];
#pragma unroll
        for (int off = 32; off >= 1; off >>= 1) {
            v1 += __shfl_down(v1, off);
            v2 += __shfl_down(v2, off);
            v3 += __shfl_down(v3, off);
        }
        if (g == 0) {
            sum_pic[b * 36 + d]      = v1 * (1.0f / 64.0f);
            sum_pic[b * 36 + 12 + d] = v2 * (1.0f / 64.0f);
            sum_pic[b * 36 + 24 + d] = v3 * (1.0f / 64.0f);
        }
    }
}

// ---------------------------------------------------------------------------
// Kernel C: single block. BN36 over the 256 pictures, then 36->18->8->2 MLP
// + softmax. Thread t owns picture t. Output: p2 (256x8) then p3 (256x2).
// ---------------------------------------------------------------------------
__global__ __launch_bounds__(256) void kC(const float* __restrict__ sum_pic,
                                          const float* __restrict__ gamma36,
                                          const float* __restrict__ beta36,
                                          const float* __restrict__ wp1,
                                          const float* __restrict__ bp1,
                                          const float* __restrict__ wp2,
                                          const float* __restrict__ bp2,
                                          const float* __restrict__ wp3,
                                          const float* __restrict__ bp3,
                                          float* __restrict__ out)
{
    const int t = threadIdx.x;  // picture
    __shared__ float sm[256 * 37];      // padded: bank = (37t+c)%32, 5 coprime 32
    __shared__ float scale[36], shift[36];

    float s[36];
#pragma unroll
    for (int c = 0; c < 36; ++c) {
        s[c] = sum_pic[t * 36 + c];
        sm[t * 37 + c] = s[c];
    }
    __syncthreads();

    if (t < 36) {
        float S = 0.f, Q = 0.f;
        for (int i = 0; i < 256; ++i) {
            const float v = sm[i * 37 + t];
            S += v;
            Q += v * v;
        }
        const float m   = S * (1.0f / 256.0f);
        const float inv = rsqrtf(Q * (1.0f / 256.0f) - m * m + 1e-5f);
        scale[t] = inv * gamma36[t];
        shift[t] = beta36[t] - m * inv * gamma36[t];
    }
    __syncthreads();

#pragma unroll
    for (int c = 0; c < 36; ++c)
        s[c] = s[c] * scale[c] + shift[c];

    float p1[18];
#pragma unroll
    for (int j = 0; j < 18; ++j) {
        float acc = bp1[j];
#pragma unroll
        for (int k = 0; k < 36; ++k) acc = fmaf(s[k], wp1[j * 36 + k], acc);
        p1[j] = leaky(acc);
    }
    float p2[8];
#pragma unroll
    for (int j = 0; j < 8; ++j) {
        float acc = bp2[j];
#pragma unroll
        for (int k = 0; k < 18; ++k) acc = fmaf(p1[k], wp2[j * 18 + k], acc);
        p2[j] = leaky(acc);
    }
    float l0 = bp3[0], l1 = bp3[1];
#pragma unroll
    for (int k = 0; k < 8; ++k) {
        l0 = fmaf(p2[k], wp3[k], l0);
        l1 = fmaf(p2[k], wp3[8 + k], l1);
    }
    const float m  = fmaxf(l0, l1);
    const float e0 = __expf(l0 - m);
    const float e1 = __expf(l1 - m);
    const float rd = 1.0f / (e0 + e1);

#pragma unroll
    for (int j = 0; j < 8; ++j) out[t * 8 + j] = p2[j];   // p2 block: [0, 2048)
    out[2048 + t * 2 + 0] = e0 * rd;                       // p3 block: [2048, 2560)
    out[2048 + t * 2 + 1] = e1 * rd;
}

extern "C" void kernel_launch(void* const* d_in, const int* in_sizes, int n_in,
                              void* d_out, int out_size, void* d_ws, size_t ws_size,
                              hipStream_t stream) {
    const float* x       = (const float*)d_in[0];
    const float* dist    = (const float*)d_in[1];
    // d_in[2] segment_ids: arange(N)//C -> uniform contiguous segments; implicit in indexing
    const float* w1      = (const float*)d_in[3];
    const float* b1      = (const float*)d_in[4];
    const float* w2      = (const float*)d_in[5];
    const float* b2      = (const float*)d_in[6];
    const float* gamma12 = (const float*)d_in[7];
    const float* beta12  = (const float*)d_in[8];
    const float* wd      = (const float*)d_in[9];
    const float* bd      = (const float*)d_in[10];
    const float* gamma36 = (const float*)d_in[11];
    const float* beta36  = (const float*)d_in[12];
    const float* wp1     = (const float*)d_in[13];
    const float* bp1     = (const float*)d_in[14];
    const float* wp2     = (const float*)d_in[15];
    const float* bp2     = (const float*)d_in[16];
    const float* wp3     = (const float*)d_in[17];
    const float* bp3     = (const float*)d_in[18];

    float* ws        = (float*)d_ws;
    float* partials  = ws;                          // NSLOT*24 floats
    float* groupSums = ws + NSLOT * 24;             // NG*12 floats
    float* sum_pic   = groupSums + (size_t)NG * 12; // B_PIC*36 floats

    // ws is re-poisoned to 0xAA before every launch; zero only the atomic targets
    hipMemsetAsync(partials, 0, NSLOT * 24 * sizeof(float), stream);

    kA<<<N_CURVES / 256, 256, 0, stream>>>(x, w1, b1, w2, b2, partials, groupSums);
    kB<<<B_PIC, G_PER_B, 0, stream>>>(partials, groupSums, dist, wd, bd,
                                      gamma12, beta12, sum_pic);
    kC<<<1, 256, 0, stream>>>(sum_pic, gamma36, beta36,
                              wp1, bp1, wp2, bp2, wp3, bp3, (float*)d_out);
}